// Round 5
// baseline (290.198 us; speedup 1.0000x reference)
//
#include <hip/hip_runtime.h>
#include <stdint.h>

#define IN_SIZE 224
#define KER 5
#define IN_CH 16
#define OUT_CH 64
#define NH 220
#define NB_TILES (NH * NH)       // 48400
#define XCH (IN_SIZE * IN_SIZE)  // 50176
#define OUT_PLANE NB_TILES
#define YSTRIDE 49280            // 220*224: bf16 y, row-padded to 224, K-dim
#define LR_OVER_NB ((float)(0.005 / 48400.0))
#define GAMMA_F 0.99f
#define ONE_MINUS_GAMMA 0.01f
#define EPS_F 0.01f

typedef __attribute__((ext_vector_type(8))) short short8;
typedef __attribute__((ext_vector_type(4))) float floatx4;

__device__ inline uint16_t f2bf(float f) {
    uint32_t u = __float_as_uint(f);
    return (uint16_t)((u + 0x7FFFu + ((u >> 16) & 1u)) >> 16);
}

// ---------------- Kernel 0: cast x to bf16 (+pads), zero y-pad columns ----------------
__global__ __launch_bounds__(256) void xcast_kernel(const float* __restrict__ x,
                                                    uint16_t* __restrict__ xb,
                                                    uint16_t* __restrict__ yb) {
    int t = blockIdx.x * 256 + threadIdx.x;  // 0..200703
    if (t < XCH * IN_CH / 4) {
        float4 v = ((const float4*)x)[t];
        ushort4 o;
        o.x = f2bf(v.x); o.y = f2bf(v.y); o.z = f2bf(v.z); o.w = f2bf(v.w);
        ((ushort4*)xb)[t] = o;
    }
    if (t < 16) {  // zero 64-elem tail pad of xb
        ushort4 z = {0, 0, 0, 0};
        ((ushort4*)(xb + XCH * IN_CH))[t] = z;
    }
    if (t < OUT_CH * NH) {  // zero y pad columns j=220..223
        int o = t / NH, i = t - o * NH;
        ushort4 z = {0, 0, 0, 0};
        *(ushort4*)(yb + o * YSTRIDE + i * IN_SIZE + NH) = z;
    }
}

// ---------------- Kernel 1: conv, 64x64 tile, 4x4 micro-tile, 1 oc/block ----------------
__global__ __launch_bounds__(256) void conv_kernel(const float* __restrict__ x,
                                                   const float* __restrict__ W,
                                                   float* __restrict__ out) {
    __shared__ float xs[68 * 68];
    const int tx = threadIdx.x & 15;
    const int ty = threadIdx.x >> 4;
    const int ti = blockIdx.y * 64;
    const int tj = blockIdx.x * 64;
    const int oc = blockIdx.z;

    float acc[16];
#pragma unroll
    for (int i = 0; i < 16; i++) acc[i] = 0.f;
    const float* W0 = W + oc * 400;

    for (int c = 0; c < IN_CH; c++) {
        __syncthreads();
        for (int s = threadIdx.x; s < 68 * 17; s += 256) {
            int row = s / 17;
            int q = s - row * 17;
            int gy = ti + row, gx = tj + 4 * q;
            float4 v = make_float4(0.f, 0.f, 0.f, 0.f);
            if (gy < IN_SIZE && gx < IN_SIZE)
                v = *(const float4*)(x + c * XCH + gy * IN_SIZE + gx);
            *(float4*)(xs + row * 68 + 4 * q) = v;
        }
        __syncthreads();

        float w0[25];
#pragma unroll
        for (int q = 0; q < 25; q++) w0[q] = W0[c * 25 + q];

#pragma unroll
        for (int rr = 0; rr < 8; rr++) {
            int row = 4 * ty + rr;
            float xr[8];
            ((float4*)xr)[0] = *(const float4*)(xs + row * 68 + 4 * tx);
            ((float4*)xr)[1] = *(const float4*)(xs + row * 68 + 4 * tx + 4);
#pragma unroll
            for (int dy = 0; dy < 4; dy++) {
                int ki = rr - dy;
                if (ki >= 0 && ki <= 4) {
#pragma unroll
                    for (int kj = 0; kj < 5; kj++) {
                        float wv = w0[ki * 5 + kj];
#pragma unroll
                        for (int dx = 0; dx < 4; dx++)
                            acc[dy * 4 + dx] = fmaf(wv, xr[dx + kj], acc[dy * 4 + dx]);
                    }
                }
            }
        }
    }

    int gj = tj + 4 * tx;
    if (gj < NH) {
#pragma unroll
        for (int dy = 0; dy < 4; dy++) {
            int gi = ti + 4 * ty + dy;
            if (gi < NH)
                *(float4*)(out + oc * OUT_PLANE + gi * NH + gj) =
                    make_float4(acc[dy * 4], acc[dy * 4 + 1], acc[dy * 4 + 2], acc[dy * 4 + 3]);
        }
    }
}

// ------- Kernel 2: inhibition (fp32 in-place) + bf16 y copy + fused colsum -------
__global__ __launch_bounds__(256) void inhib_kernel(float* __restrict__ out,
                                                    uint16_t* __restrict__ yb,
                                                    float* __restrict__ colsum) {
    int p = blockIdx.x * 256 + threadIdx.x;
    bool valid = p < NB_TILES;
    int pc = valid ? p : 0;
    int i = pc / NH;
    int j = pc - i * NH;
    float v[OUT_CH];
    float m = 0.f;
#pragma unroll
    for (int oc = 0; oc < OUT_CH; oc++) {
        float t = valid ? out[oc * OUT_PLANE + p] : 0.f;
        t = fmaxf(t, 0.f);
        v[oc] = t;
        m = fmaxf(m, t);
    }
    float inv = 1.f / (m + 1e-9f);
    __shared__ float sm[OUT_CH * 4];
    const int lane = threadIdx.x & 63, wv = threadIdx.x >> 6;
#pragma unroll
    for (int oc = 0; oc < OUT_CH; oc++) {
        float t = v[oc] * inv;
        float t2 = t * t;
        t = t2 * t2 * t;
        if (valid) {
            out[oc * OUT_PLANE + p] = t;
            yb[oc * YSTRIDE + i * IN_SIZE + j] = f2bf(t);
        }
        float r = t;
        for (int off = 32; off; off >>= 1) r += __shfl_down(r, off);
        if (lane == 0) sm[oc * 4 + wv] = r;
    }
    __syncthreads();
    if (threadIdx.x < OUT_CH) {
        int oc = threadIdx.x;
        atomicAdd(colsum + oc, sm[oc * 4] + sm[oc * 4 + 1] + sm[oc * 4 + 2] + sm[oc * 4 + 3]);
    }
}

// ---------------- Kernel 3: y^T y via bf16 MFMA, split-K (4,110), prefetched ----------------
__global__ __launch_bounds__(256) void gram_kernel(const uint16_t* __restrict__ yb,
                                                   float* __restrict__ yty) {
    const int lane = threadIdx.x & 63;
    const int bg = threadIdx.x >> 6;  // b col-group = wave
    const int ag = blockIdx.x;
    const int l15 = lane & 15, kg = (lane >> 4) * 8;
    const uint16_t* pa = yb + (16 * ag + l15) * YSTRIDE + blockIdx.y * 448 + kg;
    const uint16_t* pb = yb + (16 * bg + l15) * YSTRIDE + blockIdx.y * 448 + kg;
    floatx4 acc = {0.f, 0.f, 0.f, 0.f};
    short8 a = *(const short8*)pa;
    short8 b = *(const short8*)pb;
#pragma unroll
    for (int s = 0; s < 13; s++) {
        pa += 32; pb += 32;
        short8 an = *(const short8*)pa;
        short8 bn = *(const short8*)pb;
        acc = __builtin_amdgcn_mfma_f32_16x16x32_bf16(a, b, acc, 0, 0, 0);
        a = an; b = bn;
    }
    acc = __builtin_amdgcn_mfma_f32_16x16x32_bf16(a, b, acc, 0, 0, 0);
    int row = 16 * ag + (lane >> 4) * 4;
    int col = 16 * bg + l15;
#pragma unroll
    for (int r = 0; r < 4; r++) atomicAdd(yty + (row + r) * OUT_CH + col, acc[r]);
}

// ---------------- Kernel 4: M = y^T xf via bf16 MFMA, split-K (25,77), prefetched ----------------
__device__ inline short8 unpack_b(const uint32_t* dw, int idx, int sh) {
    union { uint32_t u[4]; short8 s8; } bu;
#pragma unroll
    for (int t = 0; t < 4; t++)
        bu.u[t] = (uint32_t)((((uint64_t)dw[idx + t + 1] << 32) | dw[idx + t]) >> sh);
    return bu.s8;
}

__global__ __launch_bounds__(256) void ytxf_kernel(const uint16_t* __restrict__ yb,
                                                   const uint16_t* __restrict__ xb,
                                                   float* __restrict__ M) {
    const int lane = threadIdx.x & 63;
    const int rg = threadIdx.x >> 6;
    const int cb = blockIdx.x;
    const int l15 = lane & 15, kg = (lane >> 4) * 8;
    const int n = 16 * cb + l15;  // 0..399
    const int c = n / 25;
    const int r = n - 25 * c;
    const int ki = r / 5, kj = r - 5 * (r / 5);
    const int idx = kj >> 1;
    const int sh = (kj & 1) * 16;

    const uint16_t* pa = yb + (16 * rg + l15) * YSTRIDE + blockIdx.y * 640 + kg;
    const uint16_t* pb = xb + c * XCH + ki * IN_SIZE + blockIdx.y * 640 + kg;

    floatx4 acc = {0.f, 0.f, 0.f, 0.f};
    uint32_t dw[7], dwn[7];
    dw[6] = 0u; dwn[6] = 0u;
    short8 a = *(const short8*)pa;
    *(uint4*)dw = *(const uint4*)pb;
    *(uint2*)(dw + 4) = *(const uint2*)(pb + 8);
#pragma unroll
    for (int s = 0; s < 19; s++) {
        pa += 32; pb += 32;
        short8 an = *(const short8*)pa;
        *(uint4*)dwn = *(const uint4*)pb;
        *(uint2*)(dwn + 4) = *(const uint2*)(pb + 8);
        short8 b = unpack_b(dw, idx, sh);
        acc = __builtin_amdgcn_mfma_f32_16x16x32_bf16(a, b, acc, 0, 0, 0);
        a = an;
#pragma unroll
        for (int t = 0; t < 6; t++) dw[t] = dwn[t];
    }
    short8 b = unpack_b(dw, idx, sh);
    acc = __builtin_amdgcn_mfma_f32_16x16x32_bf16(a, b, acc, 0, 0, 0);

    int row = 16 * rg + (lane >> 4) * 4;
#pragma unroll
    for (int r2 = 0; r2 < 4; r2++) atomicAdd(M + (row + r2) * 400 + n, acc[r2]);
}

// ---------------- Kernel 5: Wfinal (+ fused exp_new/gfp) ----------------
__global__ __launch_bounds__(256) void finalize_w_kernel(const float* __restrict__ W,
                                                         const float* __restrict__ yty,
                                                         const float* __restrict__ M,
                                                         const float* __restrict__ colsum,
                                                         const float* __restrict__ exp_avg,
                                                         float* __restrict__ Wout,
                                                         float* __restrict__ expout) {
    __shared__ float gfps[OUT_CH];
    if (threadIdx.x < OUT_CH) {
        int o = threadIdx.x;
        float e = GAMMA_F * exp_avg[o] + ONE_MINUS_GAMMA * (colsum[o] / (float)NB_TILES);
        float s = e;
        for (int off = 32; off; off >>= 1) s += __shfl_down(s, off);
        s = __shfl(s, 0);
        float A = e / (s / (float)OUT_CH);
        gfps[o] = EPS_F * tanhf(-EPS_F * (A - 1.f)) + 1.f;
        if (blockIdx.x == 0) expout[o] = e;
    }
    __syncthreads();
    int idx = blockIdx.x * 256 + threadIdx.x;
    int o = idx / 400;
    int q = idx - o * 400;
    float dot = 0.f;
#pragma unroll 8
    for (int k = 0; k < OUT_CH; k++) dot = fmaf(yty[o * 64 + k], W[k * 400 + q], dot);
    float w = W[idx] + LR_OVER_NB * (M[idx] - dot);
    w = fmaxf(w, 0.f);
    float gp = gfps[o];
    float pos = (w > 0.f ? w : 0.f) * gp;
    float neg = (w < 0.f ? w : 0.f) / gp;
    Wout[idx] = pos + neg;
}

extern "C" void kernel_launch(void* const* d_in, const int* in_sizes, int n_in,
                              void* d_out, int out_size, void* d_ws, size_t ws_size,
                              hipStream_t stream) {
    const float* x = (const float*)d_in[0];
    const float* W = (const float*)d_in[1];
    const float* exp_avg = (const float*)d_in[2];
    float* out = (float*)d_out;

    float* wsf = (float*)d_ws;
    float* yty = wsf;              // 4096
    float* colsum = wsf + 4096;    // 64
    float* M = wsf + 4160;         // 25600  (ends at 29760)
    uint16_t* ybf = (uint16_t*)((char*)d_ws + 29824 * sizeof(float));  // 64*49280 bf16
    uint16_t* xbf = ybf + OUT_CH * YSTRIDE;                            // 802816+64 bf16

    float* Wout = out + OUT_CH * OUT_PLANE;
    float* expout = Wout + OUT_CH * IN_CH * KER * KER;

    hipMemsetAsync(d_ws, 0, 29760 * sizeof(float), stream);  // yty|colsum|M

    xcast_kernel<<<784, 256, 0, stream>>>(x, xbf, ybf);
    conv_kernel<<<dim3(4, 4, 64), 256, 0, stream>>>(x, W, out);
    inhib_kernel<<<190, 256, 0, stream>>>(out, ybf, colsum);
    gram_kernel<<<dim3(4, 110), 256, 0, stream>>>(ybf, yty);
    ytxf_kernel<<<dim3(25, 77), 256, 0, stream>>>(ybf, xbf, M);
    finalize_w_kernel<<<100, 256, 0, stream>>>(W, yty, M, colsum, exp_avg, Wout, expout);
}